// Round 6
// baseline (347.707 us; speedup 1.0000x reference)
//
#include <hip/hip_runtime.h>
#include <math.h>

typedef unsigned short u16;
typedef unsigned int   u32;
typedef unsigned long long u64;

#define T_PRED 30
#define BN 2048
#define DD 256
#define DHH 128
#define ESHIFT 64.0f

typedef __attribute__((ext_vector_type(8))) short short8;   // 8 x bf16
typedef __attribute__((ext_vector_type(4))) float f32x4;

// ---- workspace layout (~38.3 MB) ----
// 0: f32 nce_acc | 8: u32 done
#define WS_S      4096                     // f32 S[29][2048] partial exp-sums
#define WS_TABLE  (WS_S + 237568)          // u64 table[2048]
#define WS_LSE    (WS_TABLE + 16384)       // f32 lse29[2048]
#define WS_WH     (WS_LSE + 8192)          // u16 W^T hi [30][128][256]
#define WS_WL     (WS_WH + 1966080)
#define WS_RH     (WS_WL + 1966080)        // u16 rep hi [2048][128]
#define WS_RL     (WS_RH + 524288)
#define WS_GH     (WS_RL + 524288)         // u16 G hi [30][2048][128]
#define WS_GL29   (WS_GH + 15728640)       // u16 G lo (t=29) [2048][128]
#define WS_T29    (WS_GL29 + 524288)       // f32 tot29 [2048][2048]

__device__ __forceinline__ u16 bf16_rne(float f) {
    u32 u = __float_as_uint(f);
    u32 r = u + 0x7fffu + ((u >> 16) & 1u);
    return (u16)(r >> 16);
}

__device__ __forceinline__ short8 pack_hi8(const float* f) {   // truncation split
    short8 r;
#pragma unroll
    for (int k = 0; k < 8; ++k) r[k] = (short)(u16)(__float_as_uint(f[k]) >> 16);
    return r;
}
__device__ __forceinline__ short8 pack_lo8(const float* f) {
    short8 r;
#pragma unroll
    for (int k = 0; k < 8; ++k) {
        float hf = __uint_as_float(__float_as_uint(f[k]) & 0xffff0000u);
        r[k] = (short)bf16_rne(f[k] - hf);
    }
    return r;
}

// ---------------- prep: W transpose+split, rep split ----------------------
__global__ __launch_bounds__(256) void prep_kernel(
    const float* __restrict__ rep, const float* __restrict__ Ww,
    u16* __restrict__ Rh, u16* __restrict__ Rl,
    u16* __restrict__ Wh, u16* __restrict__ Wl)
{
    const int bx = blockIdx.x, tid = threadIdx.x;
    if (bx < 120) {
        __shared__ float tile[64][132];
        const int t = bx >> 2, d0 = (bx & 3) * 64;
        for (int it = 0; it < 8; ++it) {
            int idx = tid + it * 256;
            int row = idx >> 5, off = (idx & 31) * 4;
            *(float4*)&tile[row][off] =
                *(const float4*)&Ww[((size_t)t * DD + d0 + row) * DHH + off];
        }
        __syncthreads();
        const int h = tid & 127, part = tid >> 7;
        for (int dd = 0; dd < 32; ++dd) {
            int d = part * 32 + dd;
            float v = tile[d][h];
            u16 hb = bf16_rne(v);
            float hf = __uint_as_float((u32)hb << 16);
            size_t o = (size_t)t * DHH * DD + (size_t)h * DD + d0 + d;
            Wh[o] = hb;
            Wl[o] = bf16_rne(v - hf);
        }
    } else {
        int base = (bx - 120) * 256 + tid;            // float4 index, 8 blocks
        for (int p = 0; p < 32; ++p) {
            int i = base + p * 2048;
            float4 v = ((const float4*)rep)[i];
            float vv[4] = {v.x, v.y, v.z, v.w};
            u16 h[4], l[4];
#pragma unroll
            for (int k = 0; k < 4; ++k) {
                h[k] = bf16_rne(vv[k]);
                float hf = __uint_as_float((u32)h[k] << 16);
                l[k] = bf16_rne(vv[k] - hf);
            }
            ((ushort4*)Rh)[i] = make_ushort4(h[0], h[1], h[2], h[3]);
            ((ushort4*)Rl)[i] = make_ushort4(l[0], l[1], l[2], l[3]);
        }
    }
}

// ---------------- G[t] = E[t] @ W[t]^T for t<29: 1-pass, reg double-buffer -
// grid (32, 29). 64-row x 128-col tile. Prefetch stage kc+1 while mfma kc.
__global__ __launch_bounds__(256) void g_kernel(
    const float* __restrict__ E, const u16* __restrict__ Wh,
    u16* __restrict__ Gh)
{
    const int t    = blockIdx.y;
    const int row0 = blockIdx.x * 64;
    const int tid  = threadIdx.x;
    const int lane = tid & 63;
    const int w    = tid >> 6;
    const int ml   = lane & 15;
    const int quad = lane >> 4;
    const int wr   = (w & 1) * 32;
    const int wc   = (w >> 1) * 64;

    float4 ebuf[2][4];
    short8 wbuf[2][4];

    auto loadS = [&](int buf, int kc) {
#pragma unroll
        for (int i = 0; i < 2; ++i) {
            const float* ep = E + ((size_t)t * BN + row0 + wr + i * 16 + ml) * DD
                                + kc * 32 + quad * 8;
            ebuf[buf][i * 2]     = *(const float4*)ep;
            ebuf[buf][i * 2 + 1] = *(const float4*)(ep + 4);
        }
#pragma unroll
        for (int j = 0; j < 4; ++j)
            wbuf[buf][j] = *(const short8*)(Wh + (size_t)t * DHH * DD
                            + (size_t)(wc + j * 16 + ml) * DD + kc * 32 + quad * 8);
    };

    f32x4 acc[2][4];
#pragma unroll
    for (int i = 0; i < 2; ++i)
#pragma unroll
        for (int j = 0; j < 4; ++j) acc[i][j] = (f32x4){0.f, 0.f, 0.f, 0.f};

    loadS(0, 0);
#pragma unroll
    for (int kc = 0; kc < 8; ++kc) {
        if (kc < 7) loadS((kc + 1) & 1, kc + 1);
        const int pb = kc & 1;
        short8 ah[2];
#pragma unroll
        for (int i = 0; i < 2; ++i) {
            float f[8] = {ebuf[pb][i*2].x, ebuf[pb][i*2].y, ebuf[pb][i*2].z, ebuf[pb][i*2].w,
                          ebuf[pb][i*2+1].x, ebuf[pb][i*2+1].y, ebuf[pb][i*2+1].z, ebuf[pb][i*2+1].w};
            ah[i] = pack_hi8(f);
        }
#pragma unroll
        for (int i = 0; i < 2; ++i)
#pragma unroll
            for (int j = 0; j < 4; ++j)
                acc[i][j] = __builtin_amdgcn_mfma_f32_16x16x32_bf16(ah[i], wbuf[pb][j], acc[i][j], 0, 0, 0);
    }

#pragma unroll
    for (int i = 0; i < 2; ++i)
#pragma unroll
        for (int j = 0; j < 4; ++j)
#pragma unroll
            for (int r = 0; r < 4; ++r) {
                int row = row0 + wr + i * 16 + quad * 4 + r;
                int col = wc + j * 16 + ml;
                Gh[((size_t)t * BN + row) * DHH + col] = bf16_rne(acc[i][j][r]);
            }
}

// ---------------- G[29] 3-pass split: fine-grained, grid (128) -------------
// 16-row x 128-col per block; wave w covers cols w*32..w*32+32.
__global__ __launch_bounds__(256) void g29_kernel(
    const float* __restrict__ E, const u16* __restrict__ Wh,
    const u16* __restrict__ Wl, u16* __restrict__ Gh29, u16* __restrict__ Gl29)
{
    const int row0 = blockIdx.x * 16;
    const int tid  = threadIdx.x;
    const int lane = tid & 63;
    const int w    = tid >> 6;
    const int ml   = lane & 15;
    const int quad = lane >> 4;
    const int wc   = w * 32;
    const size_t tE = (size_t)(T_PRED - 1) * BN * DD;
    const size_t tW = (size_t)(T_PRED - 1) * DHH * DD;

    f32x4 acc[2];
    acc[0] = (f32x4){0.f, 0.f, 0.f, 0.f};
    acc[1] = (f32x4){0.f, 0.f, 0.f, 0.f};

#pragma unroll
    for (int kc = 0; kc < 8; ++kc) {
        const float* ep = E + tE + (size_t)(row0 + ml) * DD + kc * 32 + quad * 8;
        float4 e0 = *(const float4*)ep;
        float4 e1 = *(const float4*)(ep + 4);
        float f[8] = {e0.x, e0.y, e0.z, e0.w, e1.x, e1.y, e1.z, e1.w};
        short8 ah = pack_hi8(f);
        short8 al = pack_lo8(f);
#pragma unroll
        for (int j = 0; j < 2; ++j) {
            size_t o = tW + (size_t)(wc + j * 16 + ml) * DD + kc * 32 + quad * 8;
            short8 bh = *(const short8*)(Wh + o);
            short8 bl = *(const short8*)(Wl + o);
            acc[j] = __builtin_amdgcn_mfma_f32_16x16x32_bf16(ah, bh, acc[j], 0, 0, 0);
            acc[j] = __builtin_amdgcn_mfma_f32_16x16x32_bf16(ah, bl, acc[j], 0, 0, 0);
            acc[j] = __builtin_amdgcn_mfma_f32_16x16x32_bf16(al, bh, acc[j], 0, 0, 0);
        }
    }

#pragma unroll
    for (int j = 0; j < 2; ++j)
#pragma unroll
        for (int r = 0; r < 4; ++r) {
            int row = row0 + quad * 4 + r;
            int col = wc + j * 16 + ml;
            float v = acc[j][r];
            u16 hb = bf16_rne(v);
            float hf = __uint_as_float((u32)hb << 16);
            Gh29[(size_t)row * DHH + col] = hb;
            Gl29[(size_t)row * DHH + col] = bf16_rne(v - hf);
        }
}

// ---------------- nce for t=0..28: flat 32-stage loop, reg double-buffer ---
// grid (16 rowblk, 2 colhalf, 29 t). Block: 128 rows x 1024 cols.
__global__ __launch_bounds__(256) void nceA_kernel(
    const u16* __restrict__ Gh, const u16* __restrict__ Rh,
    float* __restrict__ S, float* __restrict__ nce_acc)
{
    const int row0   = blockIdx.x * 128;
    const int cchunk = blockIdx.y * 1024;
    const int t      = blockIdx.z;
    const int tid  = threadIdx.x;
    const int lane = tid & 63;
    const int w    = tid >> 6;
    const int ml   = lane & 15;
    const int quad = lane >> 4;
    const int wr   = (w >> 1) * 64;
    const int wc   = (w & 1) * 64;
    const bool dblk = ((row0 >> 10) == (int)blockIdx.y);

    short8 ah[4][4];
#pragma unroll
    for (int i = 0; i < 4; ++i)
#pragma unroll
        for (int kc = 0; kc < 4; ++kc)
            ah[i][kc] = *(const short8*)(Gh +
                ((size_t)t * BN + row0 + wr + i * 16 + ml) * DHH + kc * 32 + quad * 8);

    short8 bhbuf[2][4];
    auto loadB = [&](int buf, int c0, int kc) {
#pragma unroll
        for (int j = 0; j < 4; ++j)
            bhbuf[buf][j] = *(const short8*)(Rh +
                (size_t)(c0 + wc + j * 16 + ml) * DHH + kc * 32 + quad * 8);
    };

    float ssum[4][4];
#pragma unroll
    for (int i = 0; i < 4; ++i)
#pragma unroll
        for (int r = 0; r < 4; ++r) ssum[i][r] = 0.f;
    float dsum = 0.f;

    f32x4 acc[4][4];
#pragma unroll
    for (int i = 0; i < 4; ++i)
#pragma unroll
        for (int j = 0; j < 4; ++j) acc[i][j] = (f32x4){0.f, 0.f, 0.f, 0.f};

    loadB(0, cchunk, 0);
#pragma unroll
    for (int s = 0; s < 32; ++s) {
        const int c0 = cchunk + (s >> 2) * 128;
        const int kc = s & 3;
        const int pb = s & 1;
        if (s < 31) {
            const int sn = s + 1;
            loadB(sn & 1, cchunk + (sn >> 2) * 128, sn & 3);
        }
#pragma unroll
        for (int i = 0; i < 4; ++i)
#pragma unroll
            for (int j = 0; j < 4; ++j)
                acc[i][j] = __builtin_amdgcn_mfma_f32_16x16x32_bf16(ah[i][kc], bhbuf[pb][j], acc[i][j], 0, 0, 0);

        if ((s & 3) == 3) {
            if (dblk && c0 == row0) {   // only tile containing the diagonal
#pragma unroll
                for (int i = 0; i < 4; ++i)
#pragma unroll
                    for (int j = 0; j < 4; ++j)
#pragma unroll
                        for (int r = 0; r < 4; ++r)
                            if (wc + j * 16 + ml == wr + i * 16 + quad * 4 + r)
                                dsum += acc[i][j][r];
            }
#pragma unroll
            for (int i = 0; i < 4; ++i)
#pragma unroll
                for (int r = 0; r < 4; ++r)
                    ssum[i][r] += __expf(acc[i][0][r] - ESHIFT)
                                + __expf(acc[i][1][r] - ESHIFT)
                                + __expf(acc[i][2][r] - ESHIFT)
                                + __expf(acc[i][3][r] - ESHIFT);
#pragma unroll
            for (int i = 0; i < 4; ++i)
#pragma unroll
                for (int j = 0; j < 4; ++j) acc[i][j] = (f32x4){0.f, 0.f, 0.f, 0.f};
        }
    }

    // reduce over the 16 ml-lanes sharing each row, then one atomic per row
#pragma unroll
    for (int i = 0; i < 4; ++i)
#pragma unroll
        for (int r = 0; r < 4; ++r) {
            float v = ssum[i][r];
#pragma unroll
            for (int o = 1; o < 16; o <<= 1) v += __shfl_xor(v, o, 64);
            if (ml == 0)
                atomicAdd(S + (size_t)t * BN + row0 + wr + i * 16 + quad * 4 + r, v);
        }
    if (dblk) {
        float dv = dsum;
#pragma unroll
        for (int o = 1; o < 64; o <<= 1) dv += __shfl_xor(dv, o, 64);
        if (lane == 0) atomicAdd(nce_acc, -dv);   // nce_acc holds sum(lse - diag)
    }
}

// ---------------- reduce: nce_acc += sum over (t<29, row) of (64 + log S) --
__global__ __launch_bounds__(256) void nce_reduce_kernel(
    const float* __restrict__ S, float* __restrict__ nce_acc)
{
    __shared__ float part[4];
    const int idx = blockIdx.x * 256 + threadIdx.x;   // 232*256 = 59392 exactly
    float v = ESHIFT + __logf(S[idx]);
#pragma unroll
    for (int o = 1; o < 64; o <<= 1) v += __shfl_xor(v, o, 64);
    if ((threadIdx.x & 63) == 0) part[threadIdx.x >> 6] = v;
    __syncthreads();
    if (threadIdx.x == 0)
        atomicAdd(nce_acc, part[0] + part[1] + part[2] + part[3]);
}

// ---------------- tot29 = G[29] @ rep^T, full 3-pass split, LDS-free -------
__global__ __launch_bounds__(256) void tot29_kernel(
    const u16* __restrict__ Gh29, const u16* __restrict__ Gl29,
    const u16* __restrict__ Rh, const u16* __restrict__ Rl,
    float* __restrict__ tot29)
{
    const int row0 = blockIdx.x * 128;
    const int col0 = blockIdx.y * 128;
    const int tid  = threadIdx.x;
    const int lane = tid & 63;
    const int w    = tid >> 6;
    const int ml   = lane & 15;
    const int quad = lane >> 4;
    const int wr   = (w >> 1) * 64;
    const int wc   = (w & 1) * 64;

    f32x4 acc[4][4];
#pragma unroll
    for (int i = 0; i < 4; ++i)
#pragma unroll
        for (int j = 0; j < 4; ++j) acc[i][j] = (f32x4){0.f, 0.f, 0.f, 0.f};

#pragma unroll 2
    for (int kc = 0; kc < 4; ++kc) {
        short8 ah[4], al[4], bh[4], bl[4];
#pragma unroll
        for (int i = 0; i < 4; ++i) {
            size_t o = (size_t)(row0 + wr + i * 16 + ml) * DHH + kc * 32 + quad * 8;
            ah[i] = *(const short8*)(Gh29 + o);
            al[i] = *(const short8*)(Gl29 + o);
        }
#pragma unroll
        for (int j = 0; j < 4; ++j) {
            size_t o = (size_t)(col0 + wc + j * 16 + ml) * DHH + kc * 32 + quad * 8;
            bh[j] = *(const short8*)(Rh + o);
            bl[j] = *(const short8*)(Rl + o);
        }
#pragma unroll
        for (int i = 0; i < 4; ++i)
#pragma unroll
            for (int j = 0; j < 4; ++j) {
                acc[i][j] = __builtin_amdgcn_mfma_f32_16x16x32_bf16(ah[i], bh[j], acc[i][j], 0, 0, 0);
                acc[i][j] = __builtin_amdgcn_mfma_f32_16x16x32_bf16(ah[i], bl[j], acc[i][j], 0, 0, 0);
                acc[i][j] = __builtin_amdgcn_mfma_f32_16x16x32_bf16(al[i], bh[j], acc[i][j], 0, 0, 0);
            }
    }

#pragma unroll
    for (int i = 0; i < 4; ++i)
#pragma unroll
        for (int j = 0; j < 4; ++j)
#pragma unroll
            for (int r = 0; r < 4; ++r)
                tot29[(size_t)(row0 + wr + i * 16 + quad * 4 + r) * BN
                      + col0 + wc + j * 16 + ml] = acc[i][j][r];
}

// ---------------- lse29 per row + t=29 nce contribution --------------------
__global__ __launch_bounds__(256) void lse29_kernel(
    const float* __restrict__ tot29, float* __restrict__ lse29,
    float* __restrict__ nce_acc)
{
    __shared__ float part[4];
    const int lane = threadIdx.x & 63;
    const int wv   = threadIdx.x >> 6;
    const int row  = blockIdx.x * 4 + wv;
    const float* rp = tot29 + (size_t)row * BN;

    float ss = 0.f;
#pragma unroll 1
    for (int p = 0; p < 8; ++p) {
        float4 v = *(const float4*)&rp[p * 256 + lane * 4];
        ss += __expf(v.x - ESHIFT) + __expf(v.y - ESHIFT)
            + __expf(v.z - ESHIFT) + __expf(v.w - ESHIFT);
    }
#pragma unroll
    for (int o = 1; o < 64; o <<= 1) ss += __shfl_xor(ss, o, 64);
    if (lane == 0) {
        float lse = ESHIFT + __logf(ss);
        lse29[row] = lse;
        part[wv] = lse - rp[row];           // lse - diag
    }
    __syncthreads();
    if (threadIdx.x == 0)
        atomicAdd(nce_acc, part[0] + part[1] + part[2] + part[3]);
}

// ---------------- argmax + count + final outputs (last-block pattern) ------
__device__ __forceinline__ u32 fenc(float f) {
    u32 u = __float_as_uint(f);
    return (u & 0x80000000u) ? ~u : (u | 0x80000000u);
}

__global__ __launch_bounds__(256) void argmax_fin_kernel(
    const float* __restrict__ tot29, const float* __restrict__ lse29,
    u64* __restrict__ table, u32* __restrict__ done,
    const float* __restrict__ nce_acc, float* __restrict__ out)
{
    __shared__ u32 lastflag;
    __shared__ int cpart[4];
    const int tid = threadIdx.x;
    const int c   = blockIdx.x * 256 + tid;
    const int b0  = blockIdx.y * 128;

    float best = -3.4e38f; int bi = 0;
    for (int b = b0; b < b0 + 128; ++b) {
        float v = tot29[(size_t)b * BN + c] - lse29[b];
        if (v > best) { best = v; bi = b; }
    }
    u64 key = ((u64)fenc(best) << 32) | (u32)(0xFFFFFFFFu - (u32)bi);
    atomicMax(table + c, key);

    __threadfence();
    if (tid == 0) lastflag = (atomicAdd(done, 1u) == 127u);
    __syncthreads();
    if (!lastflag) return;

    int cnt = 0;
    for (int i = tid; i < BN; i += 256) {
        u64 k = atomicAdd(table + i, 0ull);      // device-coherent read
        u32 b = 0xFFFFFFFFu - (u32)(k & 0xFFFFFFFFull);
        if ((int)b == i) cnt++;
    }
#pragma unroll
    for (int o = 1; o < 64; o <<= 1) cnt += __shfl_xor(cnt, o, 64);
    if ((tid & 63) == 0) cpart[tid >> 6] = cnt;
    __syncthreads();
    if (tid == 0) {
        int correct = cpart[0] + cpart[1] + cpart[2] + cpart[3];
        float nce = atomicAdd((float*)nce_acc, 0.0f);
        out[0] = (float)correct / (float)BN;
        out[1] = nce / (float)(BN * T_PRED);
        out[2] = (float)BN;
        out[3] = (float)(BN * T_PRED);
    }
}

extern "C" void kernel_launch(void* const* d_in, const int* in_sizes, int n_in,
                              void* d_out, int out_size, void* d_ws, size_t ws_size,
                              hipStream_t stream) {
    const float* E   = (const float*)d_in[0];   // [T,B,D]
    const float* rep = (const float*)d_in[1];   // [B,DH]
    const float* Ww  = (const float*)d_in[2];   // [T,D,DH]
    float* out = (float*)d_out;

    char* ws = (char*)d_ws;
    float* nce_acc = (float*)(ws + 0);
    u32*   done    = (u32*)(ws + 8);
    float* S       = (float*)(ws + WS_S);
    u64*   table   = (u64*)(ws + WS_TABLE);
    float* lse29   = (float*)(ws + WS_LSE);
    u16*   Wh      = (u16*)(ws + WS_WH);
    u16*   Wl      = (u16*)(ws + WS_WL);
    u16*   Rh      = (u16*)(ws + WS_RH);
    u16*   Rl      = (u16*)(ws + WS_RL);
    u16*   Gh      = (u16*)(ws + WS_GH);
    u16*   Gh29    = Gh + (size_t)(T_PRED - 1) * BN * DHH;
    u16*   Gl29    = (u16*)(ws + WS_GL29);
    float* tot29   = (float*)(ws + WS_T29);

    hipMemsetAsync(ws, 0, WS_LSE, stream);      // nce_acc, done, S, table
    prep_kernel<<<dim3(128), 256, 0, stream>>>(rep, Ww, Rh, Rl, Wh, Wl);
    g_kernel<<<dim3(32, 29), 256, 0, stream>>>(E, Wh, Gh);
    g29_kernel<<<dim3(128), 256, 0, stream>>>(E, Wh, Wl, Gh29, Gl29);
    nceA_kernel<<<dim3(16, 2, 29), 256, 0, stream>>>(Gh, Rh, S, nce_acc);
    nce_reduce_kernel<<<dim3(232), 256, 0, stream>>>(S, nce_acc);
    tot29_kernel<<<dim3(16, 16), 256, 0, stream>>>(Gh29, Gl29, Rh, Rl, tot29);
    lse29_kernel<<<dim3(512), 256, 0, stream>>>(tot29, lse29, nce_acc);
    argmax_fin_kernel<<<dim3(8, 16), 256, 0, stream>>>(tot29, lse29, table, done,
                                                       nce_acc, out);
}

// Round 7
// 242.619 us; speedup vs baseline: 1.4331x; 1.4331x over previous
//
#include <hip/hip_runtime.h>
#include <math.h>

typedef unsigned short u16;
typedef unsigned int   u32;
typedef unsigned long long u64;

#define T_PRED 30
#define BN 2048
#define DD 256
#define DHH 128
#define ESHIFT 64.0f

typedef __attribute__((ext_vector_type(8))) short short8;   // 8 x bf16
typedef __attribute__((ext_vector_type(4))) float f32x4;

// ---- workspace layout (~38.3 MB) ----
// 0: f32 nce_acc | 8: u32 done
#define WS_S      4096                     // f32 S[30][2048] fixed-shift exp sums
#define WS_TABLE  (WS_S + 245760)          // u64 table[2048]
#define WS_WH     (WS_TABLE + 16384)       // u16 W^T hi [30][128][256]
#define WS_WL     (WS_WH + 1966080)        // u16 W^T lo (t=29 slot used)
#define WS_RH     (WS_WL + 1966080)        // u16 rep hi [2048][128]
#define WS_RL     (WS_RH + 524288)
#define WS_GH     (WS_RL + 524288)         // u16 G hi [30][2048][128]
#define WS_GL29   (WS_GH + 15728640)       // u16 G lo (t=29) [2048][128]
#define WS_T29    (WS_GL29 + 524288)       // f32 tot29 [2048][2048]

__device__ __forceinline__ u16 bf16_rne(float f) {
    u32 u = __float_as_uint(f);
    u32 r = u + 0x7fffu + ((u >> 16) & 1u);
    return (u16)(r >> 16);
}

__device__ __forceinline__ short8 pack_hi8(const float* f) {   // truncation split
    short8 r;
#pragma unroll
    for (int k = 0; k < 8; ++k) r[k] = (short)(u16)(__float_as_uint(f[k]) >> 16);
    return r;
}
__device__ __forceinline__ short8 pack_lo8(const float* f) {
    short8 r;
#pragma unroll
    for (int k = 0; k < 8; ++k) {
        float hf = __uint_as_float(__float_as_uint(f[k]) & 0xffff0000u);
        r[k] = (short)bf16_rne(f[k] - hf);
    }
    return r;
}

#define AS1 __attribute__((address_space(1)))
#define AS3 __attribute__((address_space(3)))

// ---------------- prep: W transpose+split (lo only t=29), rep split --------
__global__ __launch_bounds__(256) void prep_kernel(
    const float* __restrict__ rep, const float* __restrict__ Ww,
    u16* __restrict__ Rh, u16* __restrict__ Rl,
    u16* __restrict__ Wh, u16* __restrict__ Wl)
{
    const int bx = blockIdx.x, tid = threadIdx.x;
    if (bx < 120) {
        __shared__ float tile[64][132];
        const int t = bx >> 2, d0 = (bx & 3) * 64;
        for (int it = 0; it < 8; ++it) {
            int idx = tid + it * 256;
            int row = idx >> 5, off = (idx & 31) * 4;
            *(float4*)&tile[row][off] =
                *(const float4*)&Ww[((size_t)t * DD + d0 + row) * DHH + off];
        }
        __syncthreads();
        const int h = tid >> 1, half = tid & 1;    // h 0..127, d-half 0..1
        const bool lo = (t == T_PRED - 1);
        for (int d4 = 0; d4 < 32; d4 += 4) {
            ushort4 hv, lv;
            u16* hp = (u16*)&hv; u16* lp = (u16*)&lv;
#pragma unroll
            for (int k = 0; k < 4; ++k) {
                float v = tile[half * 32 + d4 + k][h];
                u16 hb = bf16_rne(v);
                hp[k] = hb;
                float hf = __uint_as_float((u32)hb << 16);
                lp[k] = bf16_rne(v - hf);
            }
            size_t o = (size_t)t * DHH * DD + (size_t)h * DD + d0 + half * 32 + d4;
            *(ushort4*)&Wh[o] = hv;
            if (lo) *(ushort4*)&Wl[o] = lv;
        }
    } else {
        int base = (bx - 120) * 256 + tid;            // float4 index, 8 blocks
        for (int p = 0; p < 32; ++p) {
            int i = base + p * 2048;
            float4 v = ((const float4*)rep)[i];
            float vv[4] = {v.x, v.y, v.z, v.w};
            u16 h[4], l[4];
#pragma unroll
            for (int k = 0; k < 4; ++k) {
                h[k] = bf16_rne(vv[k]);
                float hf = __uint_as_float((u32)h[k] << 16);
                l[k] = bf16_rne(vv[k] - hf);
            }
            ((ushort4*)Rh)[i] = make_ushort4(h[0], h[1], h[2], h[3]);
            ((ushort4*)Rl)[i] = make_ushort4(l[0], l[1], l[2], l[3]);
        }
    }
}

// ---------------- g: G[t]=E[t]@W[t]^T, t<29, LDS-staged E+W, 1-pass --------
// grid (32,29), block = 64 rows x 128 h-cols. Per kc: stage E 64x32 fp32 (8KB,
// swizzled slot=(unit+row)&7) + W 128x32 bf16 (8KB, slot=(unit+col)&3).
__global__ __launch_bounds__(256) void g_kernel(
    const float* __restrict__ E, const u16* __restrict__ Wh,
    u16* __restrict__ Gh)
{
    __shared__ __attribute__((aligned(16))) u32 esm[2048];   // 8 KB E fp32
    __shared__ __attribute__((aligned(16))) u16 wsm[4096];   // 8 KB W bf16
    const int t    = blockIdx.y;
    const int row0 = blockIdx.x * 64;
    const int tid  = threadIdx.x;
    const int lane = tid & 63;
    const int w    = tid >> 6;
    const int ml   = lane & 15;
    const int quad = lane >> 4;
    const int wr   = (w & 1) * 32;
    const int wc   = (w >> 1) * 64;
    const float* Et = E + (size_t)t * BN * DD;
    const u16*   Wt = Wh + (size_t)t * DHH * DD;

    f32x4 acc[2][4];
#pragma unroll
    for (int i = 0; i < 2; ++i)
#pragma unroll
        for (int j = 0; j < 4; ++j) acc[i][j] = (f32x4){0.f, 0.f, 0.f, 0.f};

#pragma unroll 1
    for (int kc = 0; kc < 8; ++kc) {
        __syncthreads();
        // stage E: 8 instrs total (2/wave). instr q: rows q*8..+8
#pragma unroll
        for (int n = 0; n < 2; ++n) {
            int q = w * 2 + n;
            int row = q * 8 + (lane >> 3);
            int unit = ((lane & 7) - row) & 7;
            const float* g = Et + (size_t)(row0 + row) * DD + kc * 32 + unit * 4;
            __builtin_amdgcn_global_load_lds((const AS1 u32*)g,
                (AS3 u32*)(&esm[q * 256]), 16, 0, 0);
        }
        // stage W: 8 instrs total (2/wave). instr q: cols q*16..+16
#pragma unroll
        for (int n = 0; n < 2; ++n) {
            int q = w * 2 + n;
            int col = q * 16 + (lane >> 2);
            int unit = ((lane & 3) - col) & 3;
            const u16* g = Wt + (size_t)col * DD + kc * 32 + unit * 8;
            __builtin_amdgcn_global_load_lds((const AS1 u32*)g,
                (AS3 u32*)(&wsm[q * 512]), 16, 0, 0);
        }
        __syncthreads();

        short8 ah[2], bh[4];
#pragma unroll
        for (int i = 0; i < 2; ++i) {
            int row = wr + i * 16 + ml;
            float4 f0 = *(const float4*)&esm[row * 32 + (((quad * 2 + 0 + row) & 7) * 4)];
            float4 f1 = *(const float4*)&esm[row * 32 + (((quad * 2 + 1 + row) & 7) * 4)];
            float f[8] = {f0.x, f0.y, f0.z, f0.w, f1.x, f1.y, f1.z, f1.w};
            ah[i] = pack_hi8(f);
        }
#pragma unroll
        for (int j = 0; j < 4; ++j) {
            int col = wc + j * 16 + ml;
            bh[j] = *(const short8*)&wsm[col * 32 + ((quad + col) & 3) * 8];
        }
#pragma unroll
        for (int i = 0; i < 2; ++i)
#pragma unroll
            for (int j = 0; j < 4; ++j)
                acc[i][j] = __builtin_amdgcn_mfma_f32_16x16x32_bf16(ah[i], bh[j], acc[i][j], 0, 0, 0);
    }

#pragma unroll
    for (int i = 0; i < 2; ++i)
#pragma unroll
        for (int j = 0; j < 4; ++j)
#pragma unroll
            for (int r = 0; r < 4; ++r) {
                int row = row0 + wr + i * 16 + quad * 4 + r;
                int col = wc + j * 16 + ml;
                Gh[((size_t)t * BN + row) * DHH + col] = bf16_rne(acc[i][j][r]);
            }
}

// ---------------- G[29] 3-pass split: fine-grained, grid (128) -------------
__global__ __launch_bounds__(256) void g29_kernel(
    const float* __restrict__ E, const u16* __restrict__ Wh,
    const u16* __restrict__ Wl, u16* __restrict__ Gh29, u16* __restrict__ Gl29)
{
    const int row0 = blockIdx.x * 16;
    const int tid  = threadIdx.x;
    const int lane = tid & 63;
    const int w    = tid >> 6;
    const int ml   = lane & 15;
    const int quad = lane >> 4;
    const int wc   = w * 32;
    const size_t tE = (size_t)(T_PRED - 1) * BN * DD;
    const size_t tW = (size_t)(T_PRED - 1) * DHH * DD;

    f32x4 acc[2];
    acc[0] = (f32x4){0.f, 0.f, 0.f, 0.f};
    acc[1] = (f32x4){0.f, 0.f, 0.f, 0.f};

#pragma unroll
    for (int kc = 0; kc < 8; ++kc) {
        const float* ep = E + tE + (size_t)(row0 + ml) * DD + kc * 32 + quad * 8;
        float4 e0 = *(const float4*)ep;
        float4 e1 = *(const float4*)(ep + 4);
        float f[8] = {e0.x, e0.y, e0.z, e0.w, e1.x, e1.y, e1.z, e1.w};
        short8 ah = pack_hi8(f);
        short8 al = pack_lo8(f);
#pragma unroll
        for (int j = 0; j < 2; ++j) {
            size_t o = tW + (size_t)(wc + j * 16 + ml) * DD + kc * 32 + quad * 8;
            short8 bh = *(const short8*)(Wh + o);
            short8 bl = *(const short8*)(Wl + o);
            acc[j] = __builtin_amdgcn_mfma_f32_16x16x32_bf16(ah, bh, acc[j], 0, 0, 0);
            acc[j] = __builtin_amdgcn_mfma_f32_16x16x32_bf16(ah, bl, acc[j], 0, 0, 0);
            acc[j] = __builtin_amdgcn_mfma_f32_16x16x32_bf16(al, bh, acc[j], 0, 0, 0);
        }
    }

#pragma unroll
    for (int j = 0; j < 2; ++j)
#pragma unroll
        for (int r = 0; r < 4; ++r) {
            int row = row0 + quad * 4 + r;
            int col = wc + j * 16 + ml;
            float v = acc[j][r];
            u16 hb = bf16_rne(v);
            float hf = __uint_as_float((u32)hb << 16);
            Gh29[(size_t)row * DHH + col] = hb;
            Gl29[(size_t)row * DHH + col] = bf16_rne(v - hf);
        }
}

// ---------------- nceA: t<29, LDS-staged B, reg A, fixed-shift -------------
// grid (16,2,29), block = 128 rows x 1024 cols (8 c0-tiles of 128).
// B LDS layout: [col][k] 256B rows as 16x16B units, slot=(unit+col)&15.
__global__ __launch_bounds__(256) void nceA_kernel(
    const u16* __restrict__ Gh, const u16* __restrict__ Rh,
    float* __restrict__ S, float* __restrict__ nce_acc)
{
    __shared__ __attribute__((aligned(16))) u16 bsm[16384];  // 32 KB
    const int row0   = blockIdx.x * 128;
    const int chalf  = blockIdx.y;
    const int cchunk = chalf * 1024;
    const int t      = blockIdx.z;
    const int tid  = threadIdx.x;
    const int lane = tid & 63;
    const int w    = tid >> 6;
    const int ml   = lane & 15;
    const int quad = lane >> 4;
    const int wr   = (w >> 1) * 64;
    const int wc   = (w & 1) * 64;
    const bool dblk = ((row0 >> 10) == chalf);

    short8 ah[4][4];
#pragma unroll
    for (int i = 0; i < 4; ++i)
#pragma unroll
        for (int kc = 0; kc < 4; ++kc)
            ah[i][kc] = *(const short8*)(Gh +
                ((size_t)t * BN + row0 + wr + i * 16 + ml) * DHH + kc * 32 + quad * 8);

    float ssum[4][4];
#pragma unroll
    for (int i = 0; i < 4; ++i)
#pragma unroll
        for (int r = 0; r < 4; ++r) ssum[i][r] = 0.f;
    float dsum = 0.f;

#pragma unroll 1
    for (int c0 = cchunk; c0 < cchunk + 1024; c0 += 128) {
        __syncthreads();
        // stage Rh tile [c0..c0+128) x 128k: 32 instrs (8/wave)
#pragma unroll
        for (int n = 0; n < 8; ++n) {
            int q = w * 8 + n;
            int col = q * 4 + (lane >> 4);
            int unit = ((lane & 15) - col) & 15;
            const u16* g = Rh + (size_t)(c0 + col) * DHH + unit * 8;
            __builtin_amdgcn_global_load_lds((const AS1 u32*)g,
                (AS3 u32*)(&bsm[q * 512]), 16, 0, 0);
        }
        __syncthreads();

        f32x4 acc[4][4];
#pragma unroll
        for (int i = 0; i < 4; ++i)
#pragma unroll
            for (int j = 0; j < 4; ++j) acc[i][j] = (f32x4){0.f, 0.f, 0.f, 0.f};

#pragma unroll
        for (int kc = 0; kc < 4; ++kc) {
            short8 bh[4];
#pragma unroll
            for (int j = 0; j < 4; ++j) {
                int col = wc + j * 16 + ml;
                bh[j] = *(const short8*)&bsm[col * 128 + (((kc << 2) + quad + col) & 15) * 8];
            }
#pragma unroll
            for (int i = 0; i < 4; ++i)
#pragma unroll
                for (int j = 0; j < 4; ++j)
                    acc[i][j] = __builtin_amdgcn_mfma_f32_16x16x32_bf16(ah[i][kc], bh[j], acc[i][j], 0, 0, 0);
        }

        if (dblk && c0 == row0) {   // only tile containing the diagonal
#pragma unroll
            for (int i = 0; i < 4; ++i)
#pragma unroll
                for (int j = 0; j < 4; ++j)
#pragma unroll
                    for (int r = 0; r < 4; ++r)
                        if (wc + j * 16 + ml == wr + i * 16 + quad * 4 + r)
                            dsum += acc[i][j][r];
        }
#pragma unroll
        for (int i = 0; i < 4; ++i)
#pragma unroll
            for (int r = 0; r < 4; ++r)
                ssum[i][r] += __expf(acc[i][0][r] - ESHIFT)
                            + __expf(acc[i][1][r] - ESHIFT)
                            + __expf(acc[i][2][r] - ESHIFT)
                            + __expf(acc[i][3][r] - ESHIFT);
    }

#pragma unroll
    for (int i = 0; i < 4; ++i)
#pragma unroll
        for (int r = 0; r < 4; ++r) {
            float v = ssum[i][r];
#pragma unroll
            for (int o = 1; o < 16; o <<= 1) v += __shfl_xor(v, o, 64);
            if (ml == 0)
                atomicAdd(S + (size_t)t * BN + row0 + wr + i * 16 + quad * 4 + r, v);
        }
    if (dblk) {
        float dv = dsum;
#pragma unroll
        for (int o = 1; o < 64; o <<= 1) dv += __shfl_xor(dv, o, 64);
        if (lane == 0) atomicAdd(nce_acc, -dv);
    }
}

// ---------------- tot29: 3-pass, LDS-staged Bh+Bl, writes tot29 + S[29] ----
// grid (32,16), block = 64 rows x 128 cols.
__global__ __launch_bounds__(256) void tot29_kernel(
    const u16* __restrict__ Gh29, const u16* __restrict__ Gl29,
    const u16* __restrict__ Rh, const u16* __restrict__ Rl,
    float* __restrict__ tot29, float* __restrict__ S29,
    float* __restrict__ nce_acc)
{
    __shared__ __attribute__((aligned(16))) u16 bsm[32768];  // 64 KB: hi | lo
    const int row0 = blockIdx.x * 64;
    const int col0 = blockIdx.y * 128;
    const int tid  = threadIdx.x;
    const int lane = tid & 63;
    const int w    = tid >> 6;
    const int ml   = lane & 15;
    const int quad = lane >> 4;
    const int wr   = (w & 1) * 32;
    const int wc   = (w >> 1) * 64;
    const bool dblk = ((int)(blockIdx.x >> 1) == (int)blockIdx.y);

    // stage Rh+Rl tile once: 64 instrs (16/wave)
#pragma unroll
    for (int n = 0; n < 16; ++n) {
        int q = w * 16 + n;
        int half = q >> 5, qq = q & 31;
        int col = qq * 4 + (lane >> 4);
        int unit = ((lane & 15) - col) & 15;
        const u16* g = (half ? Rl : Rh) + (size_t)(col0 + col) * DHH + unit * 8;
        __builtin_amdgcn_global_load_lds((const AS1 u32*)g,
            (AS3 u32*)(&bsm[half * 16384 + qq * 512]), 16, 0, 0);
    }

    short8 ah[2][4], al[2][4];
#pragma unroll
    for (int i = 0; i < 2; ++i)
#pragma unroll
        for (int kc = 0; kc < 4; ++kc) {
            size_t o = (size_t)(row0 + wr + i * 16 + ml) * DHH + kc * 32 + quad * 8;
            ah[i][kc] = *(const short8*)(Gh29 + o);
            al[i][kc] = *(const short8*)(Gl29 + o);
        }

    f32x4 acc[2][4];
#pragma unroll
    for (int i = 0; i < 2; ++i)
#pragma unroll
        for (int j = 0; j < 4; ++j) acc[i][j] = (f32x4){0.f, 0.f, 0.f, 0.f};

    __syncthreads();

#pragma unroll
    for (int kc = 0; kc < 4; ++kc) {
        short8 bh[4], bl[4];
#pragma unroll
        for (int j = 0; j < 4; ++j) {
            int col = wc + j * 16 + ml;
            int sl = (((kc << 2) + quad + col) & 15) * 8;
            bh[j] = *(const short8*)&bsm[col * 128 + sl];
            bl[j] = *(const short8*)&bsm[16384 + col * 128 + sl];
        }
#pragma unroll
        for (int i = 0; i < 2; ++i)
#pragma unroll
            for (int j = 0; j < 4; ++j) {
                acc[i][j] = __builtin_amdgcn_mfma_f32_16x16x32_bf16(ah[i][kc], bh[j], acc[i][j], 0, 0, 0);
                acc[i][j] = __builtin_amdgcn_mfma_f32_16x16x32_bf16(ah[i][kc], bl[j], acc[i][j], 0, 0, 0);
                acc[i][j] = __builtin_amdgcn_mfma_f32_16x16x32_bf16(al[i][kc], bh[j], acc[i][j], 0, 0, 0);
            }
    }

    float dsum = 0.f;
#pragma unroll
    for (int i = 0; i < 2; ++i) {
#pragma unroll
        for (int r = 0; r < 4; ++r) {
            int row = row0 + wr + i * 16 + quad * 4 + r;
            float es = 0.f;
#pragma unroll
            for (int j = 0; j < 4; ++j) {
                int col = col0 + wc + j * 16 + ml;
                float v = acc[i][j][r];
                tot29[(size_t)row * BN + col] = v;
                es += __expf(v - ESHIFT);
                if (dblk && col == row) dsum += v;
            }
#pragma unroll
            for (int o = 1; o < 16; o <<= 1) es += __shfl_xor(es, o, 64);
            if (ml == 0) atomicAdd(S29 + row, es);
        }
    }
    if (dblk) {
#pragma unroll
        for (int o = 1; o < 64; o <<= 1) dsum += __shfl_xor(dsum, o, 64);
        if (lane == 0) atomicAdd(nce_acc, -dsum);
    }
}

// ---------------- reduce: nce_acc += sum over all (t,row) of (64 + log S) --
__global__ __launch_bounds__(256) void nce_reduce_kernel(
    const float* __restrict__ S, float* __restrict__ nce_acc)
{
    __shared__ float part[4];
    const int idx = blockIdx.x * 256 + threadIdx.x;   // 240*256 = 61440 exactly
    float v = ESHIFT + __logf(S[idx]);
#pragma unroll
    for (int o = 1; o < 64; o <<= 1) v += __shfl_xor(v, o, 64);
    if ((threadIdx.x & 63) == 0) part[threadIdx.x >> 6] = v;
    __syncthreads();
    if (threadIdx.x == 0)
        atomicAdd(nce_acc, part[0] + part[1] + part[2] + part[3]);
}

// ---------------- argmax + count + final outputs (last-block pattern) ------
__device__ __forceinline__ u32 fenc(float f) {
    u32 u = __float_as_uint(f);
    return (u & 0x80000000u) ? ~u : (u | 0x80000000u);
}

__global__ __launch_bounds__(256) void argmax_fin_kernel(
    const float* __restrict__ tot29, const float* __restrict__ S29,
    u64* __restrict__ table, u32* __restrict__ done,
    const float* __restrict__ nce_acc, float* __restrict__ out)
{
    __shared__ float lse_s[128];
    __shared__ u32 lastflag;
    __shared__ int cpart[4];
    const int tid = threadIdx.x;
    const int c   = blockIdx.x * 256 + tid;
    const int b0  = blockIdx.y * 128;

    if (tid < 128) lse_s[tid] = ESHIFT + __logf(S29[b0 + tid]);
    __syncthreads();

    float best = -3.4e38f; int bi = 0;
    for (int b = 0; b < 128; ++b) {
        float v = tot29[(size_t)(b0 + b) * BN + c] - lse_s[b];
        if (v > best) { best = v; bi = b0 + b; }
    }
    u64 key = ((u64)fenc(best) << 32) | (u32)(0xFFFFFFFFu - (u32)bi);
    atomicMax(table + c, key);

    __threadfence();
    if (tid == 0) lastflag = (atomicAdd(done, 1u) == 127u);
    __syncthreads();
    if (!lastflag) return;

    int cnt = 0;
    for (int i = tid; i < BN; i += 256) {
        u64 k = atomicAdd(table + i, 0ull);      // device-coherent read
        u32 b = 0xFFFFFFFFu - (u32)(k & 0xFFFFFFFFull);
        if ((int)b == i) cnt++;
    }
#pragma unroll
    for (int o = 1; o < 64; o <<= 1) cnt += __shfl_xor(cnt, o, 64);
    if ((tid & 63) == 0) cpart[tid >> 6] = cnt;
    __syncthreads();
    if (tid == 0) {
        int correct = cpart[0] + cpart[1] + cpart[2] + cpart[3];
        float nce = atomicAdd((float*)nce_acc, 0.0f);
        out[0] = (float)correct / (float)BN;
        out[1] = nce / (float)(BN * T_PRED);
        out[2] = (float)BN;
        out[3] = (float)(BN * T_PRED);
    }
}

extern "C" void kernel_launch(void* const* d_in, const int* in_sizes, int n_in,
                              void* d_out, int out_size, void* d_ws, size_t ws_size,
                              hipStream_t stream) {
    const float* E   = (const float*)d_in[0];   // [T,B,D]
    const float* rep = (const float*)d_in[1];   // [B,DH]
    const float* Ww  = (const float*)d_in[2];   // [T,D,DH]
    float* out = (float*)d_out;

    char* ws = (char*)d_ws;
    float* nce_acc = (float*)(ws + 0);
    u32*   done    = (u32*)(ws + 8);
    float* S       = (float*)(ws + WS_S);
    float* S29     = S + (size_t)(T_PRED - 1) * BN;
    u64*   table   = (u64*)(ws + WS_TABLE);
    u16*   Wh      = (u16*)(ws + WS_WH);
    u16*   Wl      = (u16*)(ws + WS_WL);
    u16*   Rh      = (u16*)(ws + WS_RH);
    u16*   Rl      = (u16*)(ws + WS_RL);
    u16*   Gh      = (u16*)(ws + WS_GH);
    u16*   Gh29    = Gh + (size_t)(T_PRED - 1) * BN * DHH;
    u16*   Gl29    = (u16*)(ws + WS_GL29);
    float* tot29   = (float*)(ws + WS_T29);

    hipMemsetAsync(ws, 0, WS_TABLE + 16384, stream);   // acc, done, S, table
    prep_kernel<<<dim3(128), 256, 0, stream>>>(rep, Ww, Rh, Rl, Wh, Wl);
    g_kernel<<<dim3(32, 29), 256, 0, stream>>>(E, Wh, Gh);
    g29_kernel<<<dim3(128), 256, 0, stream>>>(E, Wh, Wl, Gh29, Gl29);
    nceA_kernel<<<dim3(16, 2, 29), 256, 0, stream>>>(Gh, Rh, S, nce_acc);
    tot29_kernel<<<dim3(32, 16), 256, 0, stream>>>(Gh29, Gl29, Rh, Rl, tot29, S29, nce_acc);
    nce_reduce_kernel<<<dim3(240), 256, 0, stream>>>(S, nce_acc);
    argmax_fin_kernel<<<dim3(8, 16), 256, 0, stream>>>(tot29, S29, table, done,
                                                       nce_acc, out);
}

// Round 8
// 238.527 us; speedup vs baseline: 1.4577x; 1.0172x over previous
//
#include <hip/hip_runtime.h>
#include <math.h>

typedef unsigned short u16;
typedef unsigned int   u32;
typedef unsigned long long u64;

#define T_PRED 30
#define BN 2048
#define DD 256
#define DHH 128
#define ESHIFT 64.0f

typedef __attribute__((ext_vector_type(8))) short short8;   // 8 x bf16
typedef __attribute__((ext_vector_type(4))) float f32x4;

// ---- workspace layout (~38.3 MB) ----
// 0: f32 nce_acc | 8: u32 done
#define WS_S      4096                     // f32 S[30][2048] fixed-shift exp sums
#define WS_TABLE  (WS_S + 245760)          // u64 table[2048]
#define WS_WH     (WS_TABLE + 16384)       // u16 W^T hi [30][128][256]
#define WS_WL     (WS_WH + 1966080)        // u16 W^T lo (t=29 slot used)
#define WS_RH     (WS_WL + 1966080)        // u16 rep hi [2048][128]
#define WS_RL     (WS_RH + 524288)
#define WS_GH     (WS_RL + 524288)         // u16 G hi [30][2048][128]
#define WS_GL29   (WS_GH + 15728640)       // u16 G lo (t=29) [2048][128]
#define WS_T29    (WS_GL29 + 524288)       // f32 tot29 [2048][2048]

__device__ __forceinline__ u16 bf16_rne(float f) {
    u32 u = __float_as_uint(f);
    u32 r = u + 0x7fffu + ((u >> 16) & 1u);
    return (u16)(r >> 16);
}

__device__ __forceinline__ short8 pack_hi8(const float* f) {   // truncation split
    short8 r;
#pragma unroll
    for (int k = 0; k < 8; ++k) r[k] = (short)(u16)(__float_as_uint(f[k]) >> 16);
    return r;
}
__device__ __forceinline__ short8 pack_lo8(const float* f) {
    short8 r;
#pragma unroll
    for (int k = 0; k < 8; ++k) {
        float hf = __uint_as_float(__float_as_uint(f[k]) & 0xffff0000u);
        r[k] = (short)bf16_rne(f[k] - hf);
    }
    return r;
}

#define AS1 __attribute__((address_space(1)))
#define AS3 __attribute__((address_space(3)))

// ---------------- prep: W transpose+split (lo only t=29), rep split --------
__global__ __launch_bounds__(256) void prep_kernel(
    const float* __restrict__ rep, const float* __restrict__ Ww,
    u16* __restrict__ Rh, u16* __restrict__ Rl,
    u16* __restrict__ Wh, u16* __restrict__ Wl)
{
    const int bx = blockIdx.x, tid = threadIdx.x;
    if (bx < 120) {
        __shared__ float tile[64][132];
        const int t = bx >> 2, d0 = (bx & 3) * 64;
        for (int it = 0; it < 8; ++it) {
            int idx = tid + it * 256;
            int row = idx >> 5, off = (idx & 31) * 4;
            *(float4*)&tile[row][off] =
                *(const float4*)&Ww[((size_t)t * DD + d0 + row) * DHH + off];
        }
        __syncthreads();
        const int h = tid >> 1, half = tid & 1;    // h 0..127, d-half 0..1
        const bool lo = (t == T_PRED - 1);
        for (int d4 = 0; d4 < 32; d4 += 4) {
            ushort4 hv, lv;
            u16* hp = (u16*)&hv; u16* lp = (u16*)&lv;
#pragma unroll
            for (int k = 0; k < 4; ++k) {
                float v = tile[half * 32 + d4 + k][h];
                u16 hb = bf16_rne(v);
                hp[k] = hb;
                float hf = __uint_as_float((u32)hb << 16);
                lp[k] = bf16_rne(v - hf);
            }
            size_t o = (size_t)t * DHH * DD + (size_t)h * DD + d0 + half * 32 + d4;
            *(ushort4*)&Wh[o] = hv;
            if (lo) *(ushort4*)&Wl[o] = lv;
        }
    } else {
        int base = (bx - 120) * 256 + tid;            // float4 index, 8 blocks
        for (int p = 0; p < 32; ++p) {
            int i = base + p * 2048;
            float4 v = ((const float4*)rep)[i];
            float vv[4] = {v.x, v.y, v.z, v.w};
            u16 h[4], l[4];
#pragma unroll
            for (int k = 0; k < 4; ++k) {
                h[k] = bf16_rne(vv[k]);
                float hf = __uint_as_float((u32)h[k] << 16);
                l[k] = bf16_rne(vv[k] - hf);
            }
            ((ushort4*)Rh)[i] = make_ushort4(h[0], h[1], h[2], h[3]);
            ((ushort4*)Rl)[i] = make_ushort4(l[0], l[1], l[2], l[3]);
        }
    }
}

// ---------------- g: G[t]=E[t]@W[t]^T, t<29, 128x128 tile, LDS dbuf --------
// grid (16,29). Per kc (32k): E 128x32 fp32 (16KB, 16 instrs), W 128x32 bf16
// (8KB, 8 instrs). Prefetch kc+1 into alt buffer before computing kc.
__global__ __launch_bounds__(256) void g_kernel(
    const float* __restrict__ E, const u16* __restrict__ Wh,
    u16* __restrict__ Gh)
{
    __shared__ __attribute__((aligned(16))) u32 esm[2][4096];   // 2 x 16 KB
    __shared__ __attribute__((aligned(16))) u16 wsm[2][4096];   // 2 x 8 KB
    const int t    = blockIdx.y;
    const int row0 = blockIdx.x * 128;
    const int tid  = threadIdx.x;
    const int lane = tid & 63;
    const int w    = tid >> 6;
    const int ml   = lane & 15;
    const int quad = lane >> 4;
    const int wr   = (w >> 1) * 64;
    const int wc   = (w & 1) * 64;
    const float* Et = E + (size_t)t * BN * DD;
    const u16*   Wt = Wh + (size_t)t * DHH * DD;

    const int erow_l = lane >> 3, eunit = lane & 7;    // E staging lane split
    const int wcol_l = lane >> 2, wunit = lane & 3;    // W staging lane split

    auto stage = [&](int buf, int kc) {
#pragma unroll
        for (int n = 0; n < 4; ++n) {                  // E: 16 instrs, 4/wave
            int q = w * 4 + n;
            int row = q * 8 + erow_l;
            int unit = (eunit - row) & 7;
            const float* g = Et + (size_t)(row0 + row) * DD + kc * 32 + unit * 4;
            __builtin_amdgcn_global_load_lds((const AS1 u32*)g,
                (AS3 u32*)(&esm[buf][q * 256]), 16, 0, 0);
        }
#pragma unroll
        for (int n = 0; n < 2; ++n) {                  // W: 8 instrs, 2/wave
            int q = w * 2 + n;
            int col = q * 16 + wcol_l;
            int unit = (wunit - col) & 3;
            const u16* g = Wt + (size_t)col * DD + kc * 32 + unit * 8;
            __builtin_amdgcn_global_load_lds((const AS1 u32*)g,
                (AS3 u32*)(&wsm[buf][q * 512]), 16, 0, 0);
        }
    };

    f32x4 acc[4][4];
#pragma unroll
    for (int i = 0; i < 4; ++i)
#pragma unroll
        for (int j = 0; j < 4; ++j) acc[i][j] = (f32x4){0.f, 0.f, 0.f, 0.f};

    stage(0, 0);
    __syncthreads();
#pragma unroll 1
    for (int kc = 0; kc < 8; ++kc) {
        if (kc < 7) stage((kc + 1) & 1, kc + 1);       // prefetch across barrier
        const int pb = kc & 1;

        short8 ah[4], bh[4];
#pragma unroll
        for (int i = 0; i < 4; ++i) {
            int row = wr + i * 16 + ml;
            float4 f0 = *(const float4*)&esm[pb][row * 32 + (((quad * 2 + 0 + row) & 7) * 4)];
            float4 f1 = *(const float4*)&esm[pb][row * 32 + (((quad * 2 + 1 + row) & 7) * 4)];
            float f[8] = {f0.x, f0.y, f0.z, f0.w, f1.x, f1.y, f1.z, f1.w};
            ah[i] = pack_hi8(f);
        }
#pragma unroll
        for (int j = 0; j < 4; ++j) {
            int col = wc + j * 16 + ml;
            bh[j] = *(const short8*)&wsm[pb][col * 32 + ((quad + col) & 3) * 8];
        }
#pragma unroll
        for (int i = 0; i < 4; ++i)
#pragma unroll
            for (int j = 0; j < 4; ++j)
                acc[i][j] = __builtin_amdgcn_mfma_f32_16x16x32_bf16(ah[i], bh[j], acc[i][j], 0, 0, 0);
        __syncthreads();
    }

#pragma unroll
    for (int i = 0; i < 4; ++i)
#pragma unroll
        for (int j = 0; j < 4; ++j)
#pragma unroll
            for (int r = 0; r < 4; ++r) {
                int row = row0 + wr + i * 16 + quad * 4 + r;
                int col = wc + j * 16 + ml;
                Gh[((size_t)t * BN + row) * DHH + col] = bf16_rne(acc[i][j][r]);
            }
}

// ---------------- G[29] 3-pass split: fine-grained, grid (128) -------------
__global__ __launch_bounds__(256) void g29_kernel(
    const float* __restrict__ E, const u16* __restrict__ Wh,
    const u16* __restrict__ Wl, u16* __restrict__ Gh29, u16* __restrict__ Gl29)
{
    const int row0 = blockIdx.x * 16;
    const int tid  = threadIdx.x;
    const int lane = tid & 63;
    const int w    = tid >> 6;
    const int ml   = lane & 15;
    const int quad = lane >> 4;
    const int wc   = w * 32;
    const size_t tE = (size_t)(T_PRED - 1) * BN * DD;
    const size_t tW = (size_t)(T_PRED - 1) * DHH * DD;

    f32x4 acc[2];
    acc[0] = (f32x4){0.f, 0.f, 0.f, 0.f};
    acc[1] = (f32x4){0.f, 0.f, 0.f, 0.f};

#pragma unroll
    for (int kc = 0; kc < 8; ++kc) {
        const float* ep = E + tE + (size_t)(row0 + ml) * DD + kc * 32 + quad * 8;
        float4 e0 = *(const float4*)ep;
        float4 e1 = *(const float4*)(ep + 4);
        float f[8] = {e0.x, e0.y, e0.z, e0.w, e1.x, e1.y, e1.z, e1.w};
        short8 ah = pack_hi8(f);
        short8 al = pack_lo8(f);
#pragma unroll
        for (int j = 0; j < 2; ++j) {
            size_t o = tW + (size_t)(wc + j * 16 + ml) * DD + kc * 32 + quad * 8;
            short8 bh = *(const short8*)(Wh + o);
            short8 bl = *(const short8*)(Wl + o);
            acc[j] = __builtin_amdgcn_mfma_f32_16x16x32_bf16(ah, bh, acc[j], 0, 0, 0);
            acc[j] = __builtin_amdgcn_mfma_f32_16x16x32_bf16(ah, bl, acc[j], 0, 0, 0);
            acc[j] = __builtin_amdgcn_mfma_f32_16x16x32_bf16(al, bh, acc[j], 0, 0, 0);
        }
    }

#pragma unroll
    for (int j = 0; j < 2; ++j)
#pragma unroll
        for (int r = 0; r < 4; ++r) {
            int row = row0 + quad * 4 + r;
            int col = wc + j * 16 + ml;
            float v = acc[j][r];
            u16 hb = bf16_rne(v);
            float hf = __uint_as_float((u32)hb << 16);
            Gh29[(size_t)row * DHH + col] = hb;
            Gl29[(size_t)row * DHH + col] = bf16_rne(v - hf);
        }
}

// ---------------- nceA: t<29, LDS dbuf B, reg A, fixed-shift ---------------
// grid (16,2,29), block = 128 rows x 1024 cols (8 c0-tiles of 128).
// Prefetch tile n+1 into alt 32KB buffer before computing tile n.
__global__ __launch_bounds__(256) void nceA_kernel(
    const u16* __restrict__ Gh, const u16* __restrict__ Rh,
    float* __restrict__ S, float* __restrict__ nce_acc)
{
    __shared__ __attribute__((aligned(16))) u16 bsm[2][16384];  // 2 x 32 KB
    const int row0   = blockIdx.x * 128;
    const int chalf  = blockIdx.y;
    const int cchunk = chalf * 1024;
    const int t      = blockIdx.z;
    const int tid  = threadIdx.x;
    const int lane = tid & 63;
    const int w    = tid >> 6;
    const int ml   = lane & 15;
    const int quad = lane >> 4;
    const int wr   = (w >> 1) * 64;
    const int wc   = (w & 1) * 64;
    const bool dblk = ((row0 >> 10) == chalf);
    const int scol_l = lane >> 4, sunit = lane & 15;   // staging lane split

    auto stage = [&](int buf, int c0) {
#pragma unroll
        for (int n = 0; n < 8; ++n) {                  // 32 instrs, 8/wave
            int q = w * 8 + n;
            int col = q * 4 + scol_l;
            int unit = (sunit - col) & 15;
            const u16* g = Rh + (size_t)(c0 + col) * DHH + unit * 8;
            __builtin_amdgcn_global_load_lds((const AS1 u32*)g,
                (AS3 u32*)(&bsm[buf][q * 512]), 16, 0, 0);
        }
    };

    stage(0, cchunk);

    short8 ah[4][4];
#pragma unroll
    for (int i = 0; i < 4; ++i)
#pragma unroll
        for (int kc = 0; kc < 4; ++kc)
            ah[i][kc] = *(const short8*)(Gh +
                ((size_t)t * BN + row0 + wr + i * 16 + ml) * DHH + kc * 32 + quad * 8);

    float ssum[4][4];
#pragma unroll
    for (int i = 0; i < 4; ++i)
#pragma unroll
        for (int r = 0; r < 4; ++r) ssum[i][r] = 0.f;
    float dsum = 0.f;

    __syncthreads();
#pragma unroll 1
    for (int it = 0; it < 8; ++it) {
        const int c0 = cchunk + it * 128;
        if (it < 7) stage((it + 1) & 1, c0 + 128);     // prefetch across barrier
        const int pb = it & 1;

        f32x4 acc[4][4];
#pragma unroll
        for (int i = 0; i < 4; ++i)
#pragma unroll
            for (int j = 0; j < 4; ++j) acc[i][j] = (f32x4){0.f, 0.f, 0.f, 0.f};

#pragma unroll
        for (int kc = 0; kc < 4; ++kc) {
            short8 bh[4];
#pragma unroll
            for (int j = 0; j < 4; ++j) {
                int col = wc + j * 16 + ml;
                bh[j] = *(const short8*)&bsm[pb][col * 128 + (((kc << 2) + quad + col) & 15) * 8];
            }
#pragma unroll
            for (int i = 0; i < 4; ++i)
#pragma unroll
                for (int j = 0; j < 4; ++j)
                    acc[i][j] = __builtin_amdgcn_mfma_f32_16x16x32_bf16(ah[i][kc], bh[j], acc[i][j], 0, 0, 0);
        }

        if (dblk && c0 == row0) {   // only tile containing the diagonal
#pragma unroll
            for (int i = 0; i < 4; ++i)
#pragma unroll
                for (int j = 0; j < 4; ++j)
#pragma unroll
                    for (int r = 0; r < 4; ++r)
                        if (wc + j * 16 + ml == wr + i * 16 + quad * 4 + r)
                            dsum += acc[i][j][r];
        }
#pragma unroll
        for (int i = 0; i < 4; ++i)
#pragma unroll
            for (int r = 0; r < 4; ++r)
                ssum[i][r] += __expf(acc[i][0][r] - ESHIFT)
                            + __expf(acc[i][1][r] - ESHIFT)
                            + __expf(acc[i][2][r] - ESHIFT)
                            + __expf(acc[i][3][r] - ESHIFT);
        __syncthreads();
    }

#pragma unroll
    for (int i = 0; i < 4; ++i)
#pragma unroll
        for (int r = 0; r < 4; ++r) {
            float v = ssum[i][r];
#pragma unroll
            for (int o = 1; o < 16; o <<= 1) v += __shfl_xor(v, o, 64);
            if (ml == 0)
                atomicAdd(S + (size_t)t * BN + row0 + wr + i * 16 + quad * 4 + r, v);
        }
    if (dblk) {
        float dv = dsum;
#pragma unroll
        for (int o = 1; o < 64; o <<= 1) dv += __shfl_xor(dv, o, 64);
        if (lane == 0) atomicAdd(nce_acc, -dv);
    }
}

// ---------------- tot29: 3-pass, LDS-staged Bh+Bl, writes tot29 + S[29] ----
// grid (32,16), block = 64 rows x 128 cols.
__global__ __launch_bounds__(256) void tot29_kernel(
    const u16* __restrict__ Gh29, const u16* __restrict__ Gl29,
    const u16* __restrict__ Rh, const u16* __restrict__ Rl,
    float* __restrict__ tot29, float* __restrict__ S29,
    float* __restrict__ nce_acc)
{
    __shared__ __attribute__((aligned(16))) u16 bsm[32768];  // 64 KB: hi | lo
    const int row0 = blockIdx.x * 64;
    const int col0 = blockIdx.y * 128;
    const int tid  = threadIdx.x;
    const int lane = tid & 63;
    const int w    = tid >> 6;
    const int ml   = lane & 15;
    const int quad = lane >> 4;
    const int wr   = (w & 1) * 32;
    const int wc   = (w >> 1) * 64;
    const bool dblk = ((int)(blockIdx.x >> 1) == (int)blockIdx.y);

    // stage Rh+Rl tile once: 64 instrs (16/wave)
#pragma unroll
    for (int n = 0; n < 16; ++n) {
        int q = w * 16 + n;
        int half = q >> 5, qq = q & 31;
        int col = qq * 4 + (lane >> 4);
        int unit = ((lane & 15) - col) & 15;
        const u16* g = (half ? Rl : Rh) + (size_t)(col0 + col) * DHH + unit * 8;
        __builtin_amdgcn_global_load_lds((const AS1 u32*)g,
            (AS3 u32*)(&bsm[half * 16384 + qq * 512]), 16, 0, 0);
    }

    short8 ah[2][4], al[2][4];
#pragma unroll
    for (int i = 0; i < 2; ++i)
#pragma unroll
        for (int kc = 0; kc < 4; ++kc) {
            size_t o = (size_t)(row0 + wr + i * 16 + ml) * DHH + kc * 32 + quad * 8;
            ah[i][kc] = *(const short8*)(Gh29 + o);
            al[i][kc] = *(const short8*)(Gl29 + o);
        }

    f32x4 acc[2][4];
#pragma unroll
    for (int i = 0; i < 2; ++i)
#pragma unroll
        for (int j = 0; j < 4; ++j) acc[i][j] = (f32x4){0.f, 0.f, 0.f, 0.f};

    __syncthreads();

#pragma unroll
    for (int kc = 0; kc < 4; ++kc) {
        short8 bh[4], bl[4];
#pragma unroll
        for (int j = 0; j < 4; ++j) {
            int col = wc + j * 16 + ml;
            int sl = (((kc << 2) + quad + col) & 15) * 8;
            bh[j] = *(const short8*)&bsm[col * 128 + sl];
            bl[j] = *(const short8*)&bsm[16384 + col * 128 + sl];
        }
#pragma unroll
        for (int i = 0; i < 2; ++i)
#pragma unroll
            for (int j = 0; j < 4; ++j) {
                acc[i][j] = __builtin_amdgcn_mfma_f32_16x16x32_bf16(ah[i][kc], bh[j], acc[i][j], 0, 0, 0);
                acc[i][j] = __builtin_amdgcn_mfma_f32_16x16x32_bf16(ah[i][kc], bl[j], acc[i][j], 0, 0, 0);
                acc[i][j] = __builtin_amdgcn_mfma_f32_16x16x32_bf16(al[i][kc], bh[j], acc[i][j], 0, 0, 0);
            }
    }

    float dsum = 0.f;
#pragma unroll
    for (int i = 0; i < 2; ++i) {
#pragma unroll
        for (int r = 0; r < 4; ++r) {
            int row = row0 + wr + i * 16 + quad * 4 + r;
            float es = 0.f;
#pragma unroll
            for (int j = 0; j < 4; ++j) {
                int col = col0 + wc + j * 16 + ml;
                float v = acc[i][j][r];
                tot29[(size_t)row * BN + col] = v;
                es += __expf(v - ESHIFT);
                if (dblk && col == row) dsum += v;
            }
#pragma unroll
            for (int o = 1; o < 16; o <<= 1) es += __shfl_xor(es, o, 64);
            if (ml == 0) atomicAdd(S29 + row, es);
        }
    }
    if (dblk) {
#pragma unroll
        for (int o = 1; o < 64; o <<= 1) dsum += __shfl_xor(dsum, o, 64);
        if (lane == 0) atomicAdd(nce_acc, -dsum);
    }
}

// ---------------- reduce: nce_acc += sum over all (t,row) of (64 + log S) --
__global__ __launch_bounds__(256) void nce_reduce_kernel(
    const float* __restrict__ S, float* __restrict__ nce_acc)
{
    __shared__ float part[4];
    const int idx = blockIdx.x * 256 + threadIdx.x;   // 240*256 = 61440 exactly
    float v = ESHIFT + __logf(S[idx]);
#pragma unroll
    for (int o = 1; o < 64; o <<= 1) v += __shfl_xor(v, o, 64);
    if ((threadIdx.x & 63) == 0) part[threadIdx.x >> 6] = v;
    __syncthreads();
    if (threadIdx.x == 0)
        atomicAdd(nce_acc, part[0] + part[1] + part[2] + part[3]);
}

// ---------------- argmax + count + final outputs (last-block pattern) ------
__device__ __forceinline__ u32 fenc(float f) {
    u32 u = __float_as_uint(f);
    return (u & 0x80000000u) ? ~u : (u | 0x80000000u);
}

__global__ __launch_bounds__(256) void argmax_fin_kernel(
    const float* __restrict__ tot29, const float* __restrict__ S29,
    u64* __restrict__ table, u32* __restrict__ done,
    const float* __restrict__ nce_acc, float* __restrict__ out)
{
    __shared__ float lse_s[128];
    __shared__ u32 lastflag;
    __shared__ int cpart[4];
    const int tid = threadIdx.x;
    const int c   = blockIdx.x * 256 + tid;
    const int b0  = blockIdx.y * 128;

    if (tid < 128) lse_s[tid] = ESHIFT + __logf(S29[b0 + tid]);
    __syncthreads();

    float best = -3.4e38f; int bi = 0;
    for (int b = 0; b < 128; ++b) {
        float v = tot29[(size_t)(b0 + b) * BN + c] - lse_s[b];
        if (v > best) { best = v; bi = b0 + b; }
    }
    u64 key = ((u64)fenc(best) << 32) | (u32)(0xFFFFFFFFu - (u32)bi);
    atomicMax(table + c, key);

    __threadfence();
    if (tid == 0) lastflag = (atomicAdd(done, 1u) == 127u);
    __syncthreads();
    if (!lastflag) return;

    int cnt = 0;
    for (int i = tid; i < BN; i += 256) {
        u64 k = atomicAdd(table + i, 0ull);      // device-coherent read
        u32 b = 0xFFFFFFFFu - (u32)(k & 0xFFFFFFFFull);
        if ((int)b == i) cnt++;
    }
#pragma unroll
    for (int o = 1; o < 64; o <<= 1) cnt += __shfl_xor(cnt, o, 64);
    if ((tid & 63) == 0) cpart[tid >> 6] = cnt;
    __syncthreads();
    if (tid == 0) {
        int correct = cpart[0] + cpart[1] + cpart[2] + cpart[3];
        float nce = atomicAdd((float*)nce_acc, 0.0f);
        out[0] = (float)correct / (float)BN;
        out[1] = nce / (float)(BN * T_PRED);
        out[2] = (float)BN;
        out[3] = (float)(BN * T_PRED);
    }
}

extern "C" void kernel_launch(void* const* d_in, const int* in_sizes, int n_in,
                              void* d_out, int out_size, void* d_ws, size_t ws_size,
                              hipStream_t stream) {
    const float* E   = (const float*)d_in[0];   // [T,B,D]
    const float* rep = (const float*)d_in[1];   // [B,DH]
    const float* Ww  = (const float*)d_in[2];   // [T,D,DH]
    float* out = (float*)d_out;

    char* ws = (char*)d_ws;
    float* nce_acc = (float*)(ws + 0);
    u32*   done    = (u32*)(ws + 8);
    float* S       = (float*)(ws + WS_S);
    float* S29     = S + (size_t)(T_PRED - 1) * BN;
    u64*   table   = (u64*)(ws + WS_TABLE);
    u16*   Wh      = (u16*)(ws + WS_WH);
    u16*   Wl      = (u16*)(ws + WS_WL);
    u16*   Rh      = (u16*)(ws + WS_RH);
    u16*   Rl      = (u16*)(ws + WS_RL);
    u16*   Gh      = (u16*)(ws + WS_GH);
    u16*   Gh29    = Gh + (size_t)(T_PRED - 1) * BN * DHH;
    u16*   Gl29    = (u16*)(ws + WS_GL29);
    float* tot29   = (float*)(ws + WS_T29);

    hipMemsetAsync(ws, 0, WS_TABLE + 16384, stream);   // acc, done, S, table
    prep_kernel<<<dim3(128), 256, 0, stream>>>(rep, Ww, Rh, Rl, Wh, Wl);
    g_kernel<<<dim3(16, 29), 256, 0, stream>>>(E, Wh, Gh);
    g29_kernel<<<dim3(128), 256, 0, stream>>>(E, Wh, Wl, Gh29, Gl29);
    nceA_kernel<<<dim3(16, 2, 29), 256, 0, stream>>>(Gh, Rh, S, nce_acc);
    tot29_kernel<<<dim3(32, 16), 256, 0, stream>>>(Gh29, Gl29, Rh, Rl, tot29, S29, nce_acc);
    nce_reduce_kernel<<<dim3(240), 256, 0, stream>>>(S, nce_acc);
    argmax_fin_kernel<<<dim3(8, 16), 256, 0, stream>>>(tot29, S29, table, done,
                                                       nce_acc, out);
}

// Round 9
// 217.312 us; speedup vs baseline: 1.6000x; 1.0976x over previous
//
#include <hip/hip_runtime.h>
#include <math.h>

typedef unsigned short u16;
typedef unsigned int   u32;
typedef unsigned long long u64;

#define T_PRED 30
#define BN 2048
#define DD 256
#define DHH 128
#define ESHIFT 64.0f

typedef __attribute__((ext_vector_type(8))) short short8;   // 8 x bf16
typedef __attribute__((ext_vector_type(4))) float f32x4;

// ---- workspace layout (~38.3 MB) ----
// 0: f32 nce_acc | 8: u32 done
#define WS_S      4096                     // f32 S[30][2048] fixed-shift exp sums
#define WS_TABLE  (WS_S + 245760)          // u64 table[2048]
#define WS_ZEND   (WS_TABLE + 16384)       // end of zeroed region = 266240 B
#define WS_WH     WS_ZEND                  // u16 W^T hi [30][128][256]
#define WS_WL     (WS_WH + 1966080)        // u16 W^T lo (t=29 slot used)
#define WS_RH     (WS_WL + 1966080)        // u16 rep hi [2048][128]
#define WS_RL     (WS_RH + 524288)
#define WS_GH     (WS_RL + 524288)         // u16 G hi [30][2048][128]
#define WS_GL29   (WS_GH + 15728640)       // u16 G lo (t=29) [2048][128]
#define WS_T29    (WS_GL29 + 524288)       // f32 tot29 [2048][2048]

__device__ __forceinline__ u16 bf16_rne(float f) {
    u32 u = __float_as_uint(f);
    u32 r = u + 0x7fffu + ((u >> 16) & 1u);
    return (u16)(r >> 16);
}

__device__ __forceinline__ short8 pack_hi8(const float* f) {   // truncation split
    short8 r;
#pragma unroll
    for (int k = 0; k < 8; ++k) r[k] = (short)(u16)(__float_as_uint(f[k]) >> 16);
    return r;
}
__device__ __forceinline__ short8 pack_lo8(const float* f) {
    short8 r;
#pragma unroll
    for (int k = 0; k < 8; ++k) {
        float hf = __uint_as_float(__float_as_uint(f[k]) & 0xffff0000u);
        r[k] = (short)bf16_rne(f[k] - hf);
    }
    return r;
}

#define AS1 __attribute__((address_space(1)))
#define AS3 __attribute__((address_space(3)))

// ---------------- prep: zero accumulators + W transpose/split + rep split --
__global__ __launch_bounds__(256) void prep_kernel(
    const float* __restrict__ rep, const float* __restrict__ Ww,
    u16* __restrict__ Rh, u16* __restrict__ Rl,
    u16* __restrict__ Wh, u16* __restrict__ Wl, u32* __restrict__ wsz)
{
    const int bx = blockIdx.x, tid = threadIdx.x;
    // zero nce_acc/done/S/table: 266240 B = 66560 words over 32768 threads
    for (int i = bx * 256 + tid; i < 66560; i += 32768) wsz[i] = 0;

    if (bx < 120) {
        __shared__ float tile[64][132];
        const int t = bx >> 2, d0 = (bx & 3) * 64;
        for (int it = 0; it < 8; ++it) {
            int idx = tid + it * 256;
            int row = idx >> 5, off = (idx & 31) * 4;
            *(float4*)&tile[row][off] =
                *(const float4*)&Ww[((size_t)t * DD + d0 + row) * DHH + off];
        }
        __syncthreads();
        const int h = tid >> 1, half = tid & 1;    // h 0..127, d-half 0..1
        const bool lo = (t == T_PRED - 1);
        for (int d4 = 0; d4 < 32; d4 += 4) {
            ushort4 hv, lv;
            u16* hp = (u16*)&hv; u16* lp = (u16*)&lv;
#pragma unroll
            for (int k = 0; k < 4; ++k) {
                float v = tile[half * 32 + d4 + k][h];
                u16 hb = bf16_rne(v);
                hp[k] = hb;
                float hf = __uint_as_float((u32)hb << 16);
                lp[k] = bf16_rne(v - hf);
            }
            size_t o = (size_t)t * DHH * DD + (size_t)h * DD + d0 + half * 32 + d4;
            *(ushort4*)&Wh[o] = hv;
            if (lo) *(ushort4*)&Wl[o] = lv;
        }
    } else {
        int base = (bx - 120) * 256 + tid;            // float4 index, 8 blocks
        for (int p = 0; p < 32; ++p) {
            int i = base + p * 2048;
            float4 v = ((const float4*)rep)[i];
            float vv[4] = {v.x, v.y, v.z, v.w};
            u16 h[4], l[4];
#pragma unroll
            for (int k = 0; k < 4; ++k) {
                h[k] = bf16_rne(vv[k]);
                float hf = __uint_as_float((u32)h[k] << 16);
                l[k] = bf16_rne(vv[k] - hf);
            }
            ((ushort4*)Rh)[i] = make_ushort4(h[0], h[1], h[2], h[3]);
            ((ushort4*)Rl)[i] = make_ushort4(l[0], l[1], l[2], l[3]);
        }
    }
}

// ---------------- g_fused: y<29 -> G[t] 1-pass 128x128 dbuf; y>=29 -> G[29]
// 3-pass split (64 blocks x 32 rows). grid (16, 33), 256 thr.
__global__ __launch_bounds__(256) void g_fused_kernel(
    const float* __restrict__ E, const u16* __restrict__ Wh,
    const u16* __restrict__ Wl, u16* __restrict__ Gh,
    u16* __restrict__ Gh29, u16* __restrict__ Gl29)
{
    __shared__ __attribute__((aligned(16))) u32 esm[2][4096];   // 2 x 16 KB
    __shared__ __attribute__((aligned(16))) u16 wsm[2][4096];   // 2 x 8 KB
    const int y    = blockIdx.y;
    const int tid  = threadIdx.x;
    const int lane = tid & 63;
    const int w    = tid >> 6;
    const int ml   = lane & 15;
    const int quad = lane >> 4;

    if (y < 29) {
        const int t    = y;
        const int row0 = blockIdx.x * 128;
        const int wr   = (w >> 1) * 64;
        const int wc   = (w & 1) * 64;
        const float* Et = E + (size_t)t * BN * DD;
        const u16*   Wt = Wh + (size_t)t * DHH * DD;
        const int erow_l = lane >> 3, eunit = lane & 7;
        const int wcol_l = lane >> 2, wunit = lane & 3;

        auto stage = [&](int buf, int kc) {
#pragma unroll
            for (int n = 0; n < 4; ++n) {                  // E: 16 instrs
                int q = w * 4 + n;
                int row = q * 8 + erow_l;
                int unit = (eunit - row) & 7;
                const float* g = Et + (size_t)(row0 + row) * DD + kc * 32 + unit * 4;
                __builtin_amdgcn_global_load_lds((const AS1 u32*)g,
                    (AS3 u32*)(&esm[buf][q * 256]), 16, 0, 0);
            }
#pragma unroll
            for (int n = 0; n < 2; ++n) {                  // W: 8 instrs
                int q = w * 2 + n;
                int col = q * 16 + wcol_l;
                int unit = (wunit - col) & 3;
                const u16* g = Wt + (size_t)col * DD + kc * 32 + unit * 8;
                __builtin_amdgcn_global_load_lds((const AS1 u32*)g,
                    (AS3 u32*)(&wsm[buf][q * 512]), 16, 0, 0);
            }
        };

        f32x4 acc[4][4];
#pragma unroll
        for (int i = 0; i < 4; ++i)
#pragma unroll
            for (int j = 0; j < 4; ++j) acc[i][j] = (f32x4){0.f, 0.f, 0.f, 0.f};

        stage(0, 0);
        __syncthreads();
#pragma unroll 1
        for (int kc = 0; kc < 8; ++kc) {
            if (kc < 7) stage((kc + 1) & 1, kc + 1);
            const int pb = kc & 1;
            short8 ah[4], bh[4];
#pragma unroll
            for (int i = 0; i < 4; ++i) {
                int row = wr + i * 16 + ml;
                float4 f0 = *(const float4*)&esm[pb][row * 32 + (((quad * 2 + 0 + row) & 7) * 4)];
                float4 f1 = *(const float4*)&esm[pb][row * 32 + (((quad * 2 + 1 + row) & 7) * 4)];
                float f[8] = {f0.x, f0.y, f0.z, f0.w, f1.x, f1.y, f1.z, f1.w};
                ah[i] = pack_hi8(f);
            }
#pragma unroll
            for (int j = 0; j < 4; ++j) {
                int col = wc + j * 16 + ml;
                bh[j] = *(const short8*)&wsm[pb][col * 32 + ((quad + col) & 3) * 8];
            }
#pragma unroll
            for (int i = 0; i < 4; ++i)
#pragma unroll
                for (int j = 0; j < 4; ++j)
                    acc[i][j] = __builtin_amdgcn_mfma_f32_16x16x32_bf16(ah[i], bh[j], acc[i][j], 0, 0, 0);
            __syncthreads();
        }

#pragma unroll
        for (int i = 0; i < 4; ++i)
#pragma unroll
            for (int j = 0; j < 4; ++j)
#pragma unroll
                for (int r = 0; r < 4; ++r) {
                    int row = row0 + wr + i * 16 + quad * 4 + r;
                    int col = wc + j * 16 + ml;
                    Gh[((size_t)t * BN + row) * DHH + col] = bf16_rne(acc[i][j][r]);
                }
    } else {
        // t=29 3-pass split, rows row0..row0+32, wave w -> cols w*32..+32
        const int row0 = ((y - 29) * 16 + blockIdx.x) * 32;
        const int wc   = w * 32;
        const size_t tE = (size_t)(T_PRED - 1) * BN * DD;
        const size_t tW = (size_t)(T_PRED - 1) * DHH * DD;

#pragma unroll 1
        for (int rr = 0; rr < 32; rr += 16) {
            f32x4 acc[2];
            acc[0] = (f32x4){0.f, 0.f, 0.f, 0.f};
            acc[1] = (f32x4){0.f, 0.f, 0.f, 0.f};
#pragma unroll
            for (int kc = 0; kc < 8; ++kc) {
                const float* ep = E + tE + (size_t)(row0 + rr + ml) * DD + kc * 32 + quad * 8;
                float4 e0 = *(const float4*)ep;
                float4 e1 = *(const float4*)(ep + 4);
                float f[8] = {e0.x, e0.y, e0.z, e0.w, e1.x, e1.y, e1.z, e1.w};
                short8 ah = pack_hi8(f);
                short8 al = pack_lo8(f);
#pragma unroll
                for (int j = 0; j < 2; ++j) {
                    size_t o = tW + (size_t)(wc + j * 16 + ml) * DD + kc * 32 + quad * 8;
                    short8 bh = *(const short8*)(Wh + o);
                    short8 bl = *(const short8*)(Wl + o);
                    acc[j] = __builtin_amdgcn_mfma_f32_16x16x32_bf16(ah, bh, acc[j], 0, 0, 0);
                    acc[j] = __builtin_amdgcn_mfma_f32_16x16x32_bf16(ah, bl, acc[j], 0, 0, 0);
                    acc[j] = __builtin_amdgcn_mfma_f32_16x16x32_bf16(al, bh, acc[j], 0, 0, 0);
                }
            }
#pragma unroll
            for (int j = 0; j < 2; ++j)
#pragma unroll
                for (int r = 0; r < 4; ++r) {
                    int row = row0 + rr + quad * 4 + r;
                    int col = wc + j * 16 + ml;
                    float v = acc[j][r];
                    u16 hb = bf16_rne(v);
                    float hf = __uint_as_float((u32)hb << 16);
                    Gh29[(size_t)row * DHH + col] = hb;
                    Gl29[(size_t)row * DHH + col] = bf16_rne(v - hf);
                }
        }
    }
}

// ---------------- nce_fused: 128-thr blocks, grid (16, 4, 45) --------------
// z<29:  nceA t=z, block = 128 rows x 512 cols (8 tiles of 64), LDS dbuf 2x16KB
// z>=29: tot29 3-pass, block = 64 rows x 64 cols, LDS 32 KB single
__global__ __launch_bounds__(128) void nce_fused_kernel(
    const u16* __restrict__ Gh, const u16* __restrict__ Gh29,
    const u16* __restrict__ Gl29, const u16* __restrict__ Rh,
    const u16* __restrict__ Rl, float* __restrict__ S,
    float* __restrict__ tot29, float* __restrict__ nce_acc)
{
    __shared__ __attribute__((aligned(16))) u16 sm[16384];   // 32 KB
    const int z    = blockIdx.z;
    const int tid  = threadIdx.x;
    const int lane = tid & 63;
    const int w    = tid >> 6;          // 0..1
    const int ml   = lane & 15;
    const int quad = lane >> 4;
    float* S29 = S + (size_t)(T_PRED - 1) * BN;

    if (z < 29) {
        const int t      = z;
        const int row0   = blockIdx.x * 128;
        const int cq     = blockIdx.y;
        const int cchunk = cq * 512;
        const int wr     = w * 64;
        const bool dblk  = ((int)(blockIdx.x >> 2) == cq);
        const int scol_l = lane >> 4, sunit = lane & 15;

        auto stage = [&](int buf, int c0) {
#pragma unroll
            for (int n = 0; n < 8; ++n) {              // 16 instrs total
                int q = w * 8 + n;
                int col = q * 4 + scol_l;
                int unit = (sunit - col) & 15;
                const u16* g = Rh + (size_t)(c0 + col) * DHH + unit * 8;
                __builtin_amdgcn_global_load_lds((const AS1 u32*)g,
                    (AS3 u32*)(&sm[buf * 8192 + q * 512]), 16, 0, 0);
            }
        };

        stage(0, cchunk);

        short8 ah[4][4];
#pragma unroll
        for (int i = 0; i < 4; ++i)
#pragma unroll
            for (int kc = 0; kc < 4; ++kc)
                ah[i][kc] = *(const short8*)(Gh +
                    ((size_t)t * BN + row0 + wr + i * 16 + ml) * DHH + kc * 32 + quad * 8);

        float ssum[4][4];
#pragma unroll
        for (int i = 0; i < 4; ++i)
#pragma unroll
            for (int r = 0; r < 4; ++r) ssum[i][r] = 0.f;
        float dsum = 0.f;

        __syncthreads();
#pragma unroll 1
        for (int it = 0; it < 8; ++it) {
            const int c0 = cchunk + it * 64;
            if (it < 7) stage((it + 1) & 1, c0 + 64);
            const int pb = it & 1;

            f32x4 acc[4][4];
#pragma unroll
            for (int i = 0; i < 4; ++i)
#pragma unroll
                for (int j = 0; j < 4; ++j) acc[i][j] = (f32x4){0.f, 0.f, 0.f, 0.f};

#pragma unroll
            for (int kc = 0; kc < 4; ++kc) {
                short8 bh[4];
#pragma unroll
                for (int j = 0; j < 4; ++j) {
                    int col = j * 16 + ml;
                    bh[j] = *(const short8*)&sm[pb * 8192 + col * 128
                              + (((kc << 2) + quad + col) & 15) * 8];
                }
#pragma unroll
                for (int i = 0; i < 4; ++i)
#pragma unroll
                    for (int j = 0; j < 4; ++j)
                        acc[i][j] = __builtin_amdgcn_mfma_f32_16x16x32_bf16(ah[i][kc], bh[j], acc[i][j], 0, 0, 0);
            }

            if (dblk && c0 == row0 + wr) {   // this wave's diagonal tile
#pragma unroll
                for (int i = 0; i < 4; ++i)
#pragma unroll
                    for (int j = 0; j < 4; ++j)
#pragma unroll
                        for (int r = 0; r < 4; ++r)
                            if (j * 16 + ml == i * 16 + quad * 4 + r)
                                dsum += acc[i][j][r];
            }
#pragma unroll
            for (int i = 0; i < 4; ++i)
#pragma unroll
                for (int r = 0; r < 4; ++r)
                    ssum[i][r] += __expf(acc[i][0][r] - ESHIFT)
                                + __expf(acc[i][1][r] - ESHIFT)
                                + __expf(acc[i][2][r] - ESHIFT)
                                + __expf(acc[i][3][r] - ESHIFT);
            __syncthreads();
        }

#pragma unroll
        for (int i = 0; i < 4; ++i)
#pragma unroll
            for (int r = 0; r < 4; ++r) {
                float v = ssum[i][r];
#pragma unroll
                for (int o = 1; o < 16; o <<= 1) v += __shfl_xor(v, o, 64);
                if (ml == 0)
                    atomicAdd(S + (size_t)t * BN + row0 + wr + i * 16 + quad * 4 + r, v);
            }
        if (dblk) {
            float dv = dsum;
#pragma unroll
            for (int o = 1; o < 64; o <<= 1) dv += __shfl_xor(dv, o, 64);
            if (lane == 0) atomicAdd(nce_acc, -dv);
        }
    } else {
        // ---- tot29 path: 64 rows x 64 cols, 3-pass ----
        const int zz   = z - T_PRED + 1;
        const int row0 = (zz * 2 + (blockIdx.y >> 1)) * 64;
        const int col0 = (((int)blockIdx.x << 1) | (blockIdx.y & 1)) * 64;
        const bool dblk = (row0 == col0);

        // stage Rh (16 KB) + Rl (16 KB): 32 instrs, 16/wave
#pragma unroll
        for (int n = 0; n < 16; ++n) {
            int q = w * 16 + n;
            int half = q >> 4, qq = q & 15;
            int col = qq * 4 + (lane >> 4);
            int unit = ((lane & 15) - col) & 15;
            const u16* g = (half ? Rl : Rh) + (size_t)(col0 + col) * DHH + unit * 8;
            __builtin_amdgcn_global_load_lds((const AS1 u32*)g,
                (AS3 u32*)(&sm[q * 512]), 16, 0, 0);
        }

        short8 ah[2][4], al[2][4];
#pragma unroll
        for (int i = 0; i < 2; ++i)
#pragma unroll
            for (int kc = 0; kc < 4; ++kc) {
                size_t o = (size_t)(row0 + w * 32 + i * 16 + ml) * DHH + kc * 32 + quad * 8;
                ah[i][kc] = *(const short8*)(Gh29 + o);
                al[i][kc] = *(const short8*)(Gl29 + o);
            }

        f32x4 acc[2][4];
#pragma unroll
        for (int i = 0; i < 2; ++i)
#pragma unroll
            for (int j = 0; j < 4; ++j) acc[i][j] = (f32x4){0.f, 0.f, 0.f, 0.f};

        __syncthreads();
#pragma unroll
        for (int kc = 0; kc < 4; ++kc) {
            short8 bh[4], bl[4];
#pragma unroll
            for (int j = 0; j < 4; ++j) {
                int col = j * 16 + ml;
                int sl = (((kc << 2) + quad + col) & 15) * 8;
                bh[j] = *(const short8*)&sm[col * 128 + sl];
                bl[j] = *(const short8*)&sm[8192 + col * 128 + sl];
            }
#pragma unroll
            for (int i = 0; i < 2; ++i)
#pragma unroll
                for (int j = 0; j < 4; ++j) {
                    acc[i][j] = __builtin_amdgcn_mfma_f32_16x16x32_bf16(ah[i][kc], bh[j], acc[i][j], 0, 0, 0);
                    acc[i][j] = __builtin_amdgcn_mfma_f32_16x16x32_bf16(ah[i][kc], bl[j], acc[i][j], 0, 0, 0);
                    acc[i][j] = __builtin_amdgcn_mfma_f32_16x16x32_bf16(al[i][kc], bh[j], acc[i][j], 0, 0, 0);
                }
        }

        float dsum = 0.f;
#pragma unroll
        for (int i = 0; i < 2; ++i) {
#pragma unroll
            for (int r = 0; r < 4; ++r) {
                int row = row0 + w * 32 + i * 16 + quad * 4 + r;
                float es = 0.f;
#pragma unroll
                for (int j = 0; j < 4; ++j) {
                    int col = col0 + j * 16 + ml;
                    float v = acc[i][j][r];
                    tot29[(size_t)row * BN + col] = v;
                    es += __expf(v - ESHIFT);
                    if (dblk && col == row) dsum += v;
                }
#pragma unroll
                for (int o = 1; o < 16; o <<= 1) es += __shfl_xor(es, o, 64);
                if (ml == 0) atomicAdd(S29 + row, es);
            }
        }
        if (dblk) {
#pragma unroll
            for (int o = 1; o < 64; o <<= 1) dsum += __shfl_xor(dsum, o, 64);
            if (lane == 0) atomicAdd(nce_acc, -dsum);
        }
    }
}

// ---------------- argmax + S-reduce + count + final outputs ----------------
__device__ __forceinline__ u32 fenc(float f) {
    u32 u = __float_as_uint(f);
    return (u & 0x80000000u) ? ~u : (u | 0x80000000u);
}

__global__ __launch_bounds__(256) void argmax_fin_kernel(
    const float* __restrict__ tot29, const float* __restrict__ S,
    u64* __restrict__ table, u32* __restrict__ done,
    float* __restrict__ nce_acc, float* __restrict__ out)
{
    __shared__ float lse_s[128];
    __shared__ float part[4];
    __shared__ u32 lastflag;
    __shared__ int cpart[4];
    const int tid = threadIdx.x;
    const int c   = blockIdx.x * 256 + tid;
    const int b0  = blockIdx.y * 128;
    const float* S29 = S + (size_t)(T_PRED - 1) * BN;

    // S-reduce chunk: 128 blocks x 480 entries = 61440
    {
        const int base = ((int)blockIdx.y * 8 + (int)blockIdx.x) * 480;
        float v = 0.f;
        for (int i = tid; i < 480; i += 256)
            v += ESHIFT + __logf(S[base + i]);
#pragma unroll
        for (int o = 1; o < 64; o <<= 1) v += __shfl_xor(v, o, 64);
        if ((tid & 63) == 0) part[tid >> 6] = v;
        __syncthreads();
        if (tid == 0)
            atomicAdd(nce_acc, part[0] + part[1] + part[2] + part[3]);
    }

    if (tid < 128) lse_s[tid] = ESHIFT + __logf(S29[b0 + tid]);
    __syncthreads();

    float best = -3.4e38f; int bi = 0;
    for (int b = 0; b < 128; ++b) {
        float v = tot29[(size_t)(b0 + b) * BN + c] - lse_s[b];
        if (v > best) { best = v; bi = b0 + b; }
    }
    u64 key = ((u64)fenc(best) << 32) | (u32)(0xFFFFFFFFu - (u32)bi);
    atomicMax(table + c, key);

    __threadfence();
    if (tid == 0) lastflag = (atomicAdd(done, 1u) == 127u);
    __syncthreads();
    if (!lastflag) return;

    int cnt = 0;
    for (int i = tid; i < BN; i += 256) {
        u64 k = atomicAdd(table + i, 0ull);      // device-coherent read
        u32 b = 0xFFFFFFFFu - (u32)(k & 0xFFFFFFFFull);
        if ((int)b == i) cnt++;
    }
#pragma unroll
    for (int o = 1; o < 64; o <<= 1) cnt += __shfl_xor(cnt, o, 64);
    if ((tid & 63) == 0) cpart[tid >> 6] = cnt;
    __syncthreads();
    if (tid == 0) {
        int correct = cpart[0] + cpart[1] + cpart[2] + cpart[3];
        float nce = atomicAdd(nce_acc, 0.0f);
        out[0] = (float)correct / (float)BN;
        out[1] = nce / (float)(BN * T_PRED);
        out[2] = (float)BN;
        out[3] = (float)(BN * T_PRED);
    }
}

extern "C" void kernel_launch(void* const* d_in, const int* in_sizes, int n_in,
                              void* d_out, int out_size, void* d_ws, size_t ws_size,
                              hipStream_t stream) {
    const float* E   = (const float*)d_in[0];   // [T,B,D]
    const float* rep = (const float*)d_in[1];   // [B,DH]
    const float* Ww  = (const float*)d_in[2];   // [T,D,DH]
    float* out = (float*)d_out;

    char* ws = (char*)d_ws;
    float* nce_acc = (float*)(ws + 0);
    u32*   done    = (u32*)(ws + 8);
    float* S       = (float*)(ws + WS_S);
    u64*   table   = (u64*)(ws + WS_TABLE);
    u16*   Wh      = (u16*)(ws + WS_WH);
    u16*   Wl      = (u16*)(ws + WS_WL);
    u16*   Rh      = (u16*)(ws + WS_RH);
    u16*   Rl      = (u16*)(ws + WS_RL);
    u16*   Gh      = (u16*)(ws + WS_GH);
    u16*   Gh29    = Gh + (size_t)(T_PRED - 1) * BN * DHH;
    u16*   Gl29    = (u16*)(ws + WS_GL29);
    float* tot29   = (float*)(ws + WS_T29);

    prep_kernel<<<dim3(128), 256, 0, stream>>>(rep, Ww, Rh, Rl, Wh, Wl, (u32*)ws);
    g_fused_kernel<<<dim3(16, 33), 256, 0, stream>>>(E, Wh, Wl, Gh, Gh29, Gl29);
    nce_fused_kernel<<<dim3(16, 4, 45), 128, 0, stream>>>(Gh, Gh29, Gl29, Rh, Rl,
                                                          S, tot29, nce_acc);
    argmax_fin_kernel<<<dim3(8, 16), 256, 0, stream>>>(tot29, S, table, done,
                                                       nce_acc, out);
}